// Round 1
// baseline (920.732 us; speedup 1.0000x reference)
//
#include <hip/hip_runtime.h>
#include <hip/hip_bf16.h>

#define TSTEPS 1024
#define NIN 128
#define NL 64
#define NH 128
#define NOUT 32
#define CH 16
#define NCHUNK (TSTEPS / CH)

typedef __attribute__((ext_vector_type(8))) short short8;
typedef __attribute__((ext_vector_type(4))) float f32x4;

__device__ inline int pk2(float x, float y) {
    __hip_bfloat162 h = __float22bfloat162_rn(make_float2(x, y));
    union { __hip_bfloat162 h; int i; } u;
    u.h = h;
    return u.i;
}

__device__ inline short8 pack8(float4 r0, float4 r1) {
    union { short8 s; int i[4]; } f;
    f.i[0] = pk2(r0.x, r0.y); f.i[1] = pk2(r0.z, r0.w);
    f.i[2] = pk2(r1.x, r1.y); f.i[3] = pk2(r1.z, r1.w);
    return f.s;
}

// ---------------------------------------------------------------------------
// Fused kernel. Grid: 16 WGs x 256 thr. Each WG owns 16 batches.
//   wave 0          : consumer — the full 1024-step scan for 16 batches,
//                     single-wave (no barriers inside a step; wave-private
//                     LDS transposes, LDS ops are in-order per wave).
//   waves 1..3      : producers — stage u'(t) = C@s_t + h1 (bf16) for the
//                     NEXT 16-step chunk into a double-buffered LDS ring.
// One __syncthreads per chunk (16 steps) swaps the ring.
// ---------------------------------------------------------------------------
__launch_bounds__(256, 1)
__global__ void plrnn_fused(const float* __restrict__ input,
                            const float* __restrict__ A,
                            const float* __restrict__ W1,
                            const float* __restrict__ W2,
                            const float* __restrict__ h1,
                            const float* __restrict__ h2,
                            const float* __restrict__ C,
                            const float* __restrict__ Wout,
                            const float* __restrict__ bout,
                            float* __restrict__ out) {
    // u ring: [2][t][b][72 shorts] (64 used, permuted (q,mt,r) order, pad->odd*16B)
    __shared__ __attribute__((aligned(16))) unsigned short ubuf[2][CH * 16 * 72];
    __shared__ __attribute__((aligned(16))) unsigned short zbuf[16 * 72];
    __shared__ __attribute__((aligned(16))) unsigned short hbuf[16 * 136];

    const int lane = threadIdx.x & 63;
    const int w = threadIdx.x >> 6;
    const int c = lane & 15;   // column (batch within group)
    const int q = lane >> 4;   // quad
    const int bbase = blockIdx.x * 16;

    if (w == 0) {
        // ================= consumer =================
        short8 aw2[8][2];                       // W2 A-frags: H tiles x K(64)
        #pragma unroll
        for (int i = 0; i < 8; ++i)
            #pragma unroll
            for (int kt = 0; kt < 2; ++kt) {
                const float* p = W2 + (i * 16 + c) * NL + kt * 32 + q * 8;
                aw2[i][kt] = pack8(*(const float4*)p, *(const float4*)(p + 4));
            }
        short8 aw1[4][4];                       // W1 A-frags: Z tiles x K(128)
        #pragma unroll
        for (int lt = 0; lt < 4; ++lt)
            #pragma unroll
            for (int kt = 0; kt < 4; ++kt) {
                const float* p = W1 + (lt * 16 + c) * NH + kt * 32 + q * 8;
                aw1[lt][kt] = pack8(*(const float4*)p, *(const float4*)(p + 4));
            }
        f32x4 h2f[8];
        #pragma unroll
        for (int i = 0; i < 8; ++i) h2f[i] = *(const f32x4*)(h2 + i * 16 + q * 4);
        f32x4 af[4];
        #pragma unroll
        for (int lt = 0; lt < 4; ++lt) af[lt] = *(const f32x4*)(A + lt * 16 + q * 4);

        f32x4 zf[4] = {{0.f,0.f,0.f,0.f},{0.f,0.f,0.f,0.f},
                       {0.f,0.f,0.f,0.f},{0.f,0.f,0.f,0.f}};
        short8 bz0 = {0,0,0,0,0,0,0,0}, bz1 = {0,0,0,0,0,0,0,0};
        union US { short8 s; int i[4]; } ur0, ur1;
        f32x4 cin[4];

        for (int ch = 0; ch < NCHUNK; ++ch) {
            __syncthreads();                       // ubuf[ch&1] ready
            const unsigned short* ub = ubuf[ch & 1];
            // first step's u + cin (zf carried from previous chunk)
            {
                const unsigned short* up = ub + c * 72 + q * 16;
                ur0.s = *(const short8*)up;
                ur1.s = *(const short8*)(up + 8);
            }
            #pragma unroll
            for (int lt = 0; lt < 4; ++lt) {
                int ia = (lt < 2) ? ur0.i[(lt & 1) * 2]     : ur1.i[(lt & 1) * 2];
                int ib = (lt < 2) ? ur0.i[(lt & 1) * 2 + 1] : ur1.i[(lt & 1) * 2 + 1];
                cin[lt][0] = fmaf(zf[lt][0], af[lt][0], __int_as_float(ia << 16));
                cin[lt][1] = fmaf(zf[lt][1], af[lt][1], __int_as_float(ia & 0xffff0000));
                cin[lt][2] = fmaf(zf[lt][2], af[lt][2], __int_as_float(ib << 16));
                cin[lt][3] = fmaf(zf[lt][3], af[lt][3], __int_as_float(ib & 0xffff0000));
            }

            for (int tl = 0; tl < CH; ++tl) {
                // prefetch next step's u (stays in flight under the MFMAs)
                if (tl < CH - 1) {
                    const unsigned short* up = ub + ((tl + 1) * 16 + c) * 72 + q * 16;
                    ur0.s = *(const short8*)up;
                    ur1.s = *(const short8*)(up + 8);
                }
                // ---- MFMA1: H = relu(W2 z + h2), interleaved write/read ----
                short8 bh[4];
                #pragma unroll
                for (int kt = 0; kt < 4; ++kt) {
                    #pragma unroll
                    for (int ii = 0; ii < 2; ++ii) {
                        const int i = kt * 2 + ii;
                        f32x4 acc = __builtin_amdgcn_mfma_f32_16x16x32_bf16(aw2[i][0], bz0, h2f[i], 0, 0, 0);
                        acc = __builtin_amdgcn_mfma_f32_16x16x32_bf16(aw2[i][1], bz1, acc, 0, 0, 0);
                        *(int2*)&hbuf[c * 136 + i * 16 + q * 4] =
                            make_int2(pk2(fmaxf(acc[0], 0.f), fmaxf(acc[1], 0.f)),
                                      pk2(fmaxf(acc[2], 0.f), fmaxf(acc[3], 0.f)));
                    }
                    asm volatile("" ::: "memory");  // keep read after the 2 writes
                    bh[kt] = *(const short8*)&hbuf[c * 136 + kt * 32 + q * 8];
                }
                // ---- MFMA2: Z' = cin + W1 @ H ----
                #pragma unroll
                for (int kt = 0; kt < 4; ++kt)
                    #pragma unroll
                    for (int lt = 0; lt < 4; ++lt)
                        cin[lt] = __builtin_amdgcn_mfma_f32_16x16x32_bf16(aw1[lt][kt], bh[kt], cin[lt], 0, 0, 0);
                // clip -> new state
                #pragma unroll
                for (int lt = 0; lt < 4; ++lt)
                    #pragma unroll
                    for (int e = 0; e < 4; ++e)
                        zf[lt][e] = fminf(fmaxf(cin[lt][e], -5.f), 5.f);
                // next step's cin (fills the z-transpose latency below)
                if (tl < CH - 1) {
                    #pragma unroll
                    for (int lt = 0; lt < 4; ++lt) {
                        int ia = (lt < 2) ? ur0.i[(lt & 1) * 2]     : ur1.i[(lt & 1) * 2];
                        int ib = (lt < 2) ? ur0.i[(lt & 1) * 2 + 1] : ur1.i[(lt & 1) * 2 + 1];
                        cin[lt][0] = fmaf(zf[lt][0], af[lt][0], __int_as_float(ia << 16));
                        cin[lt][1] = fmaf(zf[lt][1], af[lt][1], __int_as_float(ia & 0xffff0000));
                        cin[lt][2] = fmaf(zf[lt][2], af[lt][2], __int_as_float(ib << 16));
                        cin[lt][3] = fmaf(zf[lt][3], af[lt][3], __int_as_float(ib & 0xffff0000));
                    }
                }
                // publish z (bf16) + reload B-frags for next step
                #pragma unroll
                for (int lt = 0; lt < 4; ++lt)
                    *(int2*)&zbuf[c * 72 + lt * 16 + q * 4] =
                        make_int2(pk2(zf[lt][0], zf[lt][1]), pk2(zf[lt][2], zf[lt][3]));
                asm volatile("" ::: "memory");
                bz0 = *(const short8*)&zbuf[c * 72 + q * 8];
                bz1 = *(const short8*)&zbuf[c * 72 + 32 + q * 8];
            }
        }

        // ---- epilogue: out = Wout @ z + bout ----
        #pragma unroll
        for (int mt = 0; mt < 2; ++mt) {
            const float* p0 = Wout + (mt * 16 + c) * NL + q * 8;
            short8 fa = pack8(*(const float4*)p0, *(const float4*)(p0 + 4));
            short8 fb = pack8(*(const float4*)(p0 + 32), *(const float4*)(p0 + 36));
            f32x4 cb = *(const f32x4*)(bout + mt * 16 + q * 4);
            f32x4 acc = __builtin_amdgcn_mfma_f32_16x16x32_bf16(fa, bz0, cb, 0, 0, 0);
            acc = __builtin_amdgcn_mfma_f32_16x16x32_bf16(fb, bz1, acc, 0, 0, 0);
            *(f32x4*)&out[(bbase + c) * NOUT + mt * 16 + q * 4] = acc;
        }
    } else {
        // ================= producers (waves 1..3) =================
        short8 cA[4][4];
        #pragma unroll
        for (int mt = 0; mt < 4; ++mt)
            #pragma unroll
            for (int kf = 0; kf < 4; ++kf) {
                const float* p = C + (mt * 16 + c) * NIN + kf * 32 + q * 8;
                cA[mt][kf] = pack8(*(const float4*)p, *(const float4*)(p + 4));
            }
        f32x4 h1f[4];
        #pragma unroll
        for (int mt = 0; mt < 4; ++mt) h1f[mt] = *(const f32x4*)(h1 + mt * 16 + q * 4);

        auto stage = [&](int chunk) {
            unsigned short* ob = ubuf[chunk & 1];
            for (int tl = w - 1; tl < CH; tl += 3) {
                const int t = chunk * CH + tl;
                const float* sr = input + ((size_t)(bbase + c) * TSTEPS + t) * NIN;
                short8 bf[4];
                #pragma unroll
                for (int kf = 0; kf < 4; ++kf)
                    bf[kf] = pack8(*(const float4*)(sr + kf * 32 + q * 8),
                                   *(const float4*)(sr + kf * 32 + q * 8 + 4));
                unsigned short* orow = ob + (tl * 16 + c) * 72 + q * 16;
                #pragma unroll
                for (int mt = 0; mt < 4; ++mt) {
                    f32x4 acc = __builtin_amdgcn_mfma_f32_16x16x32_bf16(cA[mt][0], bf[0], h1f[mt], 0, 0, 0);
                    acc = __builtin_amdgcn_mfma_f32_16x16x32_bf16(cA[mt][1], bf[1], acc, 0, 0, 0);
                    acc = __builtin_amdgcn_mfma_f32_16x16x32_bf16(cA[mt][2], bf[2], acc, 0, 0, 0);
                    acc = __builtin_amdgcn_mfma_f32_16x16x32_bf16(cA[mt][3], bf[3], acc, 0, 0, 0);
                    *(int2*)(orow + mt * 4) =
                        make_int2(pk2(acc[0], acc[1]), pk2(acc[2], acc[3]));
                }
            }
        };

        stage(0);
        for (int ch = 0; ch < NCHUNK; ++ch) {
            __syncthreads();
            if (ch + 1 < NCHUNK) stage(ch + 1);
        }
    }
}

extern "C" void kernel_launch(void* const* d_in, const int* in_sizes, int n_in,
                              void* d_out, int out_size, void* d_ws, size_t ws_size,
                              hipStream_t stream) {
    const float* input = (const float*)d_in[0];
    const float* A     = (const float*)d_in[1];
    const float* W1    = (const float*)d_in[2];
    const float* W2    = (const float*)d_in[3];
    const float* h1    = (const float*)d_in[4];
    const float* h2    = (const float*)d_in[5];
    const float* C     = (const float*)d_in[6];
    const float* Wout  = (const float*)d_in[7];
    const float* bout  = (const float*)d_in[8];
    float* out = (float*)d_out;

    plrnn_fused<<<dim3(16), dim3(256), 0, stream>>>(
        input, A, W1, W2, h1, h2, C, Wout, bout, out);
}